// Round 19
// baseline (57.228 us; speedup 1.0000x reference)
//
#include <hip/hip_runtime.h>
#include <hip/hip_bf16.h>
#include <math.h>

#define BB 2
#define CC 32
#define C8 4
#define NN 4096
#define VST 72        // LDS V tile row stride in shorts
#define LOG2E 1.4426950408889634f

typedef __attribute__((ext_vector_type(8))) short short8;
typedef __attribute__((ext_vector_type(16))) float f32x16;

static __device__ __forceinline__ short f2bf(float x) {
    return __builtin_bit_cast(short, __float2bfloat16(x));
}
static __device__ __forceinline__ unsigned int pkbf(float a, float b) {
    unsigned int ua = __builtin_bit_cast(unsigned int, a) + 0x8000u;
    unsigned int ub = __builtin_bit_cast(unsigned int, b) + 0x8000u;
    return (ua >> 16) | (ub & 0xffff0000u);
}

// ---------------- K1: QKV projection (blocks 0..63) + CAM gram c<=d (blocks 64..327) ----
__global__ __launch_bounds__(256) void k1(const float* __restrict__ x,
    const float* __restrict__ wq, const float* __restrict__ bq,
    const float* __restrict__ wk, const float* __restrict__ bk,
    const float* __restrict__ wv, const float* __restrict__ bv,
    short* __restrict__ qpk, short* __restrict__ kpk, short* __restrict__ vbf,
    float* __restrict__ eng)
{
    if (blockIdx.x >= 64) {
        int w = threadIdx.x >> 6, lane = threadIdx.x & 63;
        int pp = (blockIdx.x - 64)*4 + w;     // 0..1055
        int b = pp >= 528 ? 1 : 0;
        int t = pp - b*528;
        int c = 0, rem = t;
        while (rem >= CC - c) { rem -= CC - c; ++c; }
        int d = c + rem;
        const float4* xc = (const float4*)(x + ((size_t)b*CC + c)*NN);
        const float4* xd = (const float4*)(x + ((size_t)b*CC + d)*NN);
        float s = 0.f;
        for (int tt = lane; tt < NN/4; tt += 64) {
            float4 a = xc[tt], bb = xd[tt];
            s += a.x*bb.x + a.y*bb.y + a.z*bb.z + a.w*bb.w;
        }
        #pragma unroll
        for (int off = 32; off; off >>= 1) s += __shfl_down(s, off, 64);
        if (lane == 0) {
            eng[(b*CC + c)*CC + d] = s;
            eng[(b*CC + d)*CC + c] = s;
        }
        return;
    }
    __shared__ float swq[C8*CC], swk[C8*CC], swv[CC*CC], sbq[C8], sbk[C8], sbv[CC];
    int tid = threadIdx.x;
    for (int i = tid; i < C8*CC; i += 256) { swq[i] = wq[i]; swk[i] = wk[i]; }
    for (int i = tid; i < CC*CC; i += 256) swv[i] = wv[i];
    if (tid < C8) { sbq[tid] = bq[tid]; sbk[tid] = bk[tid]; }
    if (tid < CC) sbv[tid] = bv[tid];
    __syncthreads();
    int tl = tid & 127, oh = tid >> 7;
    int g = blockIdx.x*128 + tl;          // 0..8191
    int b = g >> 12; int n = g & (NN-1);
    const float* xb = x + (size_t)b*CC*NN + n;
    float xr[CC];
    #pragma unroll
    for (int c = 0; c < CC; ++c) xr[c] = xb[(size_t)c*NN];
    if (oh == 0) {
        float qv[C8], kv[C8];
        #pragma unroll
        for (int o = 0; o < C8; ++o) { qv[o] = sbq[o]; kv[o] = sbk[o]; }
        #pragma unroll
        for (int c = 0; c < CC; ++c) {
            float xc = xr[c];
            #pragma unroll
            for (int o = 0; o < C8; ++o) { qv[o] += swq[o*CC+c]*xc; kv[o] += swk[o*CC+c]*xc; }
        }
        short4 qs = make_short4(f2bf(qv[0]*LOG2E), f2bf(qv[1]*LOG2E),
                                f2bf(qv[2]*LOG2E), f2bf(qv[3]*LOG2E));
        short4 ks = make_short4(f2bf(kv[0]), f2bf(kv[1]), f2bf(kv[2]), f2bf(kv[3]));
        *(short4*)(qpk + ((size_t)b*NN + n)*4) = qs;
        *(short4*)(kpk + ((size_t)b*NN + n)*4) = ks;
    }
    int o0 = oh*16;
    #pragma unroll
    for (int o = 0; o < 16; ++o) {
        float av = sbv[o0+o];
        #pragma unroll
        for (int c = 0; c < CC; ++c) av += swv[(o0+o)*CC+c]*xr[c];
        vbf[((size_t)b*CC+o0+o)*NN + n] = f2bf(av);
    }
}

// ---------------- K2: R12 body; DIAG grid x2 with DISJOINT writes (no thrash) ----
// Blocks 0..255 write `out` (the real result); blocks 256..511 recompute the same
// values and write `out2` (ws scratch). Reads are shared (coherent-safe). LDS 99KB
// forces 1 block/CU -> two sequential identical rounds; per-block env == R12.
__global__ __launch_bounds__(1024, 4) void k2(const short* __restrict__ qpk,
    const short* __restrict__ kpk, const short* __restrict__ vbf,
    const float* __restrict__ eng, const float* __restrict__ wo,
    const float* __restrict__ bo, const float* __restrict__ gp,
    const float* __restrict__ gc, const float* __restrict__ x,
    float* __restrict__ out, float* __restrict__ out2)
{
    __shared__ __align__(16) char smem[99328];

    int half = blockIdx.x >> 8;           // 0: real out, 1: out2 (disjoint)
    int blk = blockIdx.x & 255;
    float* outp = half ? out2 : out;
    int b  = blk >> 7;
    int it = blk & 127;
    int i0 = it*32;
    int tid = threadIdx.x;
    int w = tid >> 6, lane = tid & 63;
    int qcol = lane & 31, h = lane >> 5;

    short* vbuf = (short*)smem + w*(32*VST);

    int rv = lane >> 1, ch = lane & 1;
    const short* vsrc = vbf + (size_t)b*CC*NN + (size_t)rv*NN + w*64 + ch*32;
    const short* ksrc = kpk + ((size_t)b*NN + w*64 + qcol)*4;

    short8 qf = {0,0,0,0,0,0,0,0};
    if (h == 0) {
        short4 qv = *(const short4*)(qpk + ((size_t)b*NN + i0 + qcol)*4);
        qf[0]=qv.x; qf[1]=qv.y; qf[2]=qv.z; qf[3]=qv.w;
    }

    f32x16 acc = {0,0,0,0,0,0,0,0,0,0,0,0,0,0,0,0};
    const f32x16 zz = {0,0,0,0,0,0,0,0,0,0,0,0,0,0,0,0};
    float se = 0.f;

    short8 cv0 = *(const short8*)(vsrc);
    short8 cv1 = *(const short8*)(vsrc + 8);
    short8 cv2 = *(const short8*)(vsrc + 16);
    short8 cv3 = *(const short8*)(vsrc + 24);
    short4 ck0 = *(const short4*)(ksrc);
    short4 ck1 = *(const short4*)(ksrc + 128);

    #pragma unroll
    for (int t = 0; t < 4; ++t) {
        int tn = t < 3 ? t + 1 : 3;
        short8 nv0 = *(const short8*)(vsrc + tn*1024);
        short8 nv1 = *(const short8*)(vsrc + tn*1024 + 8);
        short8 nv2 = *(const short8*)(vsrc + tn*1024 + 16);
        short8 nv3 = *(const short8*)(vsrc + tn*1024 + 24);
        short4 nk0 = *(const short4*)(ksrc + tn*4096);
        short4 nk1 = *(const short4*)(ksrc + tn*4096 + 128);

        short* wp = vbuf + rv*VST + ch*32;
        *(short8*)(wp)      = cv0;
        *(short8*)(wp + 8)  = cv1;
        *(short8*)(wp + 16) = cv2;
        *(short8*)(wp + 24) = cv3;

        const short* vrow = vbuf + qcol*VST;
        #pragma unroll
        for (int cI = 0; cI < 2; ++cI) {
            short8 kf = {0,0,0,0,0,0,0,0};
            if (h == 0) {
                short4 kk = cI ? ck1 : ck0;
                kf[0]=kk.x; kf[1]=kk.y; kf[2]=kk.z; kf[3]=kk.w;
            }
            f32x16 s = __builtin_amdgcn_mfma_f32_32x32x16_bf16(kf, qf, zz, 0, 0, 0);
            unsigned int u[8];
            #pragma unroll
            for (int g4 = 0; g4 < 4; ++g4) {
                float p0 = exp2f(s[4*g4]),   p1 = exp2f(s[4*g4+1]);
                float p2 = exp2f(s[4*g4+2]), p3 = exp2f(s[4*g4+3]);
                se += (p0+p1)+(p2+p3);
                u[2*g4]   = pkbf(p0,p1);
                u[2*g4+1] = pkbf(p2,p3);
            }
            int vo = cI*32 + 4*h;
            short4 a0 = *(const short4*)(vrow + vo);
            short4 a1 = *(const short4*)(vrow + vo + 8);
            short4 a2 = *(const short4*)(vrow + vo + 16);
            short4 a3 = *(const short4*)(vrow + vo + 24);
            short8 vf1 = {a0.x,a0.y,a0.z,a0.w, a1.x,a1.y,a1.z,a1.w};
            short8 pf1 = {(short)u[0],(short)(u[0]>>16),(short)u[1],(short)(u[1]>>16),
                          (short)u[2],(short)(u[2]>>16),(short)u[3],(short)(u[3]>>16)};
            acc = __builtin_amdgcn_mfma_f32_32x32x16_bf16(vf1, pf1, acc, 0, 0, 0);
            short8 vf2 = {a2.x,a2.y,a2.z,a2.w, a3.x,a3.y,a3.z,a3.w};
            short8 pf2 = {(short)u[4],(short)(u[4]>>16),(short)u[5],(short)(u[5]>>16),
                          (short)u[6],(short)(u[6]>>16),(short)u[7],(short)(u[7]>>16)};
            acc = __builtin_amdgcn_mfma_f32_32x32x16_bf16(vf2, pf2, acc, 0, 0, 0);
        }
        cv0 = nv0; cv1 = nv1; cv2 = nv2; cv3 = nv3;
        ck0 = nk0; ck1 = nk1;
    }

    se += __shfl_xor(se, 32, 64);

    // ================= in-block combine + CAM fold + projection =================
    __syncthreads();
    float* pamw = (float*)smem;      // [16][32*33]
    float* seL  = pamw + 16*1056;    // [16][32]
    float* sinv = seL  + 512;        // [32]
    float* pamn = sinv + 32;         // [32][33]
    float* xt   = pamn + 1056;       // [32][33]
    float* swo  = xt   + 1056;       // [32][33]
    float* swx  = swo  + 1056;       // [32][33]
    float* sc   = swx  + 1056;       // [32][33]
    float* seng = sc   + 1056;       // [1024]
    float* sbo  = seng + 1024;       // [32]
    float* swo2 = sbo  + 32;         // [32][33]

    #pragma unroll
    for (int r = 0; r < 16; ++r) {
        int c = (r&3) + 8*(r>>2) + 4*h;
        pamw[w*1056 + c*33 + qcol] = acc[r];
    }
    if (h == 0) seL[w*32 + qcol] = se;
    for (int i = tid; i < CC*CC; i += 1024) {
        int o = i >> 5, c2 = i & 31;
        seng[i] = eng[b*CC*CC + i];
        swo [o*33 + c2] = wo[o*64 + c2];
        swo2[o*33 + c2] = wo[o*64 + 32 + c2];
        xt  [o*33 + c2] = x[(size_t)b*CC*NN + (size_t)o*NN + i0 + c2];
    }
    if (tid < CC) sbo[tid] = bo[tid];
    __syncthreads();

    if (tid < CC) {
        float s = 0.f;
        #pragma unroll
        for (int w2 = 0; w2 < 16; ++w2) s += seL[w2*32 + tid];
        sinv[tid] = 1.f / s;
    } else if (tid >= 64 && tid < 64 + CC) {
        int r2 = tid - 64;
        float mn = seng[r2*32];
        #pragma unroll
        for (int d = 1; d < CC; ++d) mn = fminf(mn, seng[r2*32 + d]);
        float pv[CC]; float s = 0.f;
        #pragma unroll
        for (int d = 0; d < CC; ++d) { pv[d] = __expf(mn - seng[r2*32 + d]); s += pv[d]; }
        float inv = 1.f / s;
        #pragma unroll
        for (int d = 0; d < CC; ++d) sc[r2*33 + d] = pv[d]*inv;
    }
    __syncthreads();

    float gpv = gp[0], gcv = gc[0];
    for (int i = tid; i < CC*CC; i += 1024) {
        int c = i >> 5, q = i & 31;
        float s2 = 0.f;
        #pragma unroll
        for (int w2 = 0; w2 < 16; ++w2) s2 += pamw[w2*1056 + c*33 + q];
        pamn[c*33 + q] = gpv * s2 * sinv[q];
        float t2 = 0.f;
        #pragma unroll
        for (int c2 = 0; c2 < CC; ++c2) t2 += swo2[c*33 + c2] * sc[c2*33 + q];
        swx[c*33 + q] = swo[c*33 + q] + swo2[c*33 + q] + gcv * t2;
    }
    __syncthreads();

    int q = tid & 31, slot = (tid >> 5) & 31;
    float o0 = sbo[slot];
    #pragma unroll
    for (int c = 0; c < CC; ++c) {
        o0 += swo[slot*33 + c] * pamn[c*33 + q] + swx[slot*33 + c] * xt[c*33 + q];
    }
    outp[(size_t)b*CC*NN + (size_t)slot*NN + i0 + q] = o0;
}

extern "C" void kernel_launch(void* const* d_in, const int* in_sizes, int n_in,
                              void* d_out, int out_size, void* d_ws, size_t ws_size,
                              hipStream_t stream)
{
    const float* x  = (const float*)d_in[0];
    const float* wq = (const float*)d_in[1];
    const float* bq = (const float*)d_in[2];
    const float* wk = (const float*)d_in[3];
    const float* bk = (const float*)d_in[4];
    const float* wv = (const float*)d_in[5];
    const float* bv = (const float*)d_in[6];
    const float* gp = (const float*)d_in[7];
    const float* gc = (const float*)d_in[8];
    const float* wo = (const float*)d_in[9];
    const float* bo = (const float*)d_in[10];

    char* wsb = (char*)d_ws;
    short* qpk  = (short*)(wsb + 0);          // 65536 B
    short* kpk  = (short*)(wsb + 65536);      // 65536 B
    short* vbf  = (short*)(wsb + 131072);     // 524288 B
    float* eng  = (float*)(wsb + 655360);     // 8192 B
    float* out2 = (float*)(wsb + 663552);     // 1048576 B (diag duplicate output)

    k1<<<328, 256, 0, stream>>>(x, wq, bq, wk, bk, wv, bv, qpk, kpk, vbf, eng);
    // DIAGNOSTIC: x2 grid with disjoint writes -> clean k2 counters in top-5.
    k2<<<512, 1024, 0, stream>>>(qpk, kpk, vbf, eng, wo, bo, gp, gc, x,
                                 (float*)d_out, out2);
}

// Round 20
// 41.789 us; speedup vs baseline: 1.3695x; 1.3695x over previous
//
#include <hip/hip_runtime.h>
#include <hip/hip_bf16.h>
#include <math.h>

#define BB 2
#define CC 32
#define C8 4
#define NN 4096
#define VST 72        // LDS V tile row stride in shorts
#define LOG2E 1.4426950408889634f

typedef __attribute__((ext_vector_type(8))) short short8;
typedef __attribute__((ext_vector_type(4))) float f32x4;
typedef __attribute__((ext_vector_type(16))) float f32x16;

static __device__ __forceinline__ short f2bf(float x) {
    return __builtin_bit_cast(short, __float2bfloat16(x));
}
static __device__ __forceinline__ unsigned int pkbf(float a, float b) {
    unsigned int ua = __builtin_bit_cast(unsigned int, a) + 0x8000u;
    unsigned int ub = __builtin_bit_cast(unsigned int, b) + 0x8000u;
    return (ua >> 16) | (ub & 0xffff0000u);
}
static __device__ __forceinline__ short f2bfr(float a) {
    return (short)((__builtin_bit_cast(unsigned int, a) + 0x8000u) >> 16);
}

// ---------------- K1: QKV projection (blocks 0..63) + CAM gram c<=d (blocks 64..327) ----
__global__ __launch_bounds__(256) void k1(const float* __restrict__ x,
    const float* __restrict__ wq, const float* __restrict__ bq,
    const float* __restrict__ wk, const float* __restrict__ bk,
    const float* __restrict__ wv, const float* __restrict__ bv,
    short* __restrict__ qpk, short* __restrict__ kpk, short* __restrict__ vbf,
    float* __restrict__ eng)
{
    if (blockIdx.x >= 64) {
        int w = threadIdx.x >> 6, lane = threadIdx.x & 63;
        int pp = (blockIdx.x - 64)*4 + w;     // 0..1055
        int b = pp >= 528 ? 1 : 0;
        int t = pp - b*528;
        int c = 0, rem = t;
        while (rem >= CC - c) { rem -= CC - c; ++c; }
        int d = c + rem;
        const float4* xc = (const float4*)(x + ((size_t)b*CC + c)*NN);
        const float4* xd = (const float4*)(x + ((size_t)b*CC + d)*NN);
        float s = 0.f;
        for (int tt = lane; tt < NN/4; tt += 64) {
            float4 a = xc[tt], bb = xd[tt];
            s += a.x*bb.x + a.y*bb.y + a.z*bb.z + a.w*bb.w;
        }
        #pragma unroll
        for (int off = 32; off; off >>= 1) s += __shfl_down(s, off, 64);
        if (lane == 0) {
            eng[(b*CC + c)*CC + d] = s;
            eng[(b*CC + d)*CC + c] = s;
        }
        return;
    }
    __shared__ float swq[C8*CC], swk[C8*CC], swv[CC*CC], sbq[C8], sbk[C8], sbv[CC];
    int tid = threadIdx.x;
    for (int i = tid; i < C8*CC; i += 256) { swq[i] = wq[i]; swk[i] = wk[i]; }
    for (int i = tid; i < CC*CC; i += 256) swv[i] = wv[i];
    if (tid < C8) { sbq[tid] = bq[tid]; sbk[tid] = bk[tid]; }
    if (tid < CC) sbv[tid] = bv[tid];
    __syncthreads();
    int tl = tid & 127, oh = tid >> 7;
    int g = blockIdx.x*128 + tl;          // 0..8191
    int b = g >> 12; int n = g & (NN-1);
    const float* xb = x + (size_t)b*CC*NN + n;
    float xr[CC];
    #pragma unroll
    for (int c = 0; c < CC; ++c) xr[c] = xb[(size_t)c*NN];
    if (oh == 0) {
        float qv[C8], kv[C8];
        #pragma unroll
        for (int o = 0; o < C8; ++o) { qv[o] = sbq[o]; kv[o] = sbk[o]; }
        #pragma unroll
        for (int c = 0; c < CC; ++c) {
            float xc = xr[c];
            #pragma unroll
            for (int o = 0; o < C8; ++o) { qv[o] += swq[o*CC+c]*xc; kv[o] += swk[o*CC+c]*xc; }
        }
        short4 qs = make_short4(f2bf(qv[0]*LOG2E), f2bf(qv[1]*LOG2E),
                                f2bf(qv[2]*LOG2E), f2bf(qv[3]*LOG2E));
        short4 ks = make_short4(f2bf(kv[0]), f2bf(kv[1]), f2bf(kv[2]), f2bf(kv[3]));
        *(short4*)(qpk + ((size_t)b*NN + n)*4) = qs;
        *(short4*)(kpk + ((size_t)b*NN + n)*4) = ks;
    }
    int o0 = oh*16;
    #pragma unroll
    for (int o = 0; o < 16; ++o) {
        float av = sbv[o0+o];
        #pragma unroll
        for (int c = 0; c < CC; ++c) av += swv[(o0+o)*CC+c]*xr[c];
        vbf[((size_t)b*CC+o0+o)*NN + n] = f2bf(av);
    }
}

// ---------------- KWX: CAM softmax + fold, packed into MFMA A-fragments (2 blocks) ----
// W (32x64) = [ gp*wo1 | wo1+wo2+gc*(wo2 . cattn) ]; wfrag[b][t][lane][8] bf16 with
// A-frag mapping: row o=lane&31, k = 16t + (e&3) + 4*(lane>>5) + 8*(e>>2).
__global__ __launch_bounds__(256) void kwx(const float* __restrict__ eng,
    const float* __restrict__ wo, const float* __restrict__ gp,
    const float* __restrict__ gc, short* __restrict__ wfrag)
{
    __shared__ float se_[1024], sc[32*33], wx[32*36];
    int b = blockIdx.x, tid = threadIdx.x;
    for (int i = tid; i < 1024; i += 256) se_[i] = eng[b*1024 + i];
    __syncthreads();
    if (tid < CC) {
        float mn = se_[tid*32];
        #pragma unroll
        for (int d = 1; d < CC; ++d) mn = fminf(mn, se_[tid*32 + d]);
        float pv[CC]; float s = 0.f;
        #pragma unroll
        for (int d = 0; d < CC; ++d) { pv[d] = __expf(mn - se_[tid*32 + d]); s += pv[d]; }
        float inv = 1.f/s;
        #pragma unroll
        for (int d = 0; d < CC; ++d) sc[tid*33 + d] = pv[d]*inv;
    }
    __syncthreads();
    float gcv = gc[0];
    for (int i = tid; i < 1024; i += 256) {
        int o = i >> 5, d = i & 31;
        float t2 = 0.f;
        #pragma unroll
        for (int c2 = 0; c2 < CC; ++c2) t2 += wo[o*64 + 32 + c2] * sc[c2*33 + d];
        wx[o*36 + d] = wo[o*64 + d] + wo[o*64 + 32 + d] + gcv * t2;
    }
    __syncthreads();
    float gpv = gp[0];
    {
        int l = tid & 63, t = tid >> 6;       // 256 threads = 4 tiles x 64 lanes
        int o = l & 31, hh = l >> 5;
        short8 wf;
        #pragma unroll
        for (int e = 0; e < 8; ++e) {
            int k = 16*t + (e & 3) + 4*hh + 8*(e >> 2);
            float v = (k < 32) ? gpv * wo[o*64 + k] : wx[o*36 + (k - 32)];
            wf[e] = f2bfr(v);
        }
        *(short8*)(wfrag + ((size_t)(b*4 + t)*64 + l)*8) = wf;
    }
}

// ---------------- K2: R12 flash (unchanged) + lean MFMA-projection tail ----------------
__global__ __launch_bounds__(1024, 4) void k2(const short* __restrict__ qpk,
    const short* __restrict__ kpk, const short* __restrict__ vbf,
    const short* __restrict__ wfrag, const float* __restrict__ bo,
    const float* __restrict__ x, float* __restrict__ out)
{
    __shared__ __align__(16) char smem[99328];

    int blk = blockIdx.x;
    int b  = blk >> 7;
    int it = blk & 127;
    int i0 = it*32;
    int tid = threadIdx.x;
    int w = tid >> 6, lane = tid & 63;
    int qcol = lane & 31, h = lane >> 5;

    short* vbuf = (short*)smem + w*(32*VST);

    int rv = lane >> 1, ch = lane & 1;
    const short* vsrc = vbf + (size_t)b*CC*NN + (size_t)rv*NN + w*64 + ch*32;
    const short* ksrc = kpk + ((size_t)b*NN + w*64 + qcol)*4;

    short8 qf = {0,0,0,0,0,0,0,0};
    if (h == 0) {
        short4 qv = *(const short4*)(qpk + ((size_t)b*NN + i0 + qcol)*4);
        qf[0]=qv.x; qf[1]=qv.y; qf[2]=qv.z; qf[3]=qv.w;
    }

    f32x16 acc = {0,0,0,0,0,0,0,0,0,0,0,0,0,0,0,0};
    const f32x16 zz = {0,0,0,0,0,0,0,0,0,0,0,0,0,0,0,0};
    float se = 0.f;

    short8 cv0 = *(const short8*)(vsrc);
    short8 cv1 = *(const short8*)(vsrc + 8);
    short8 cv2 = *(const short8*)(vsrc + 16);
    short8 cv3 = *(const short8*)(vsrc + 24);
    short4 ck0 = *(const short4*)(ksrc);
    short4 ck1 = *(const short4*)(ksrc + 128);

    #pragma unroll
    for (int t = 0; t < 4; ++t) {
        int tn = t < 3 ? t + 1 : 3;
        short8 nv0 = *(const short8*)(vsrc + tn*1024);
        short8 nv1 = *(const short8*)(vsrc + tn*1024 + 8);
        short8 nv2 = *(const short8*)(vsrc + tn*1024 + 16);
        short8 nv3 = *(const short8*)(vsrc + tn*1024 + 24);
        short4 nk0 = *(const short4*)(ksrc + tn*4096);
        short4 nk1 = *(const short4*)(ksrc + tn*4096 + 128);

        short* wp = vbuf + rv*VST + ch*32;
        *(short8*)(wp)      = cv0;
        *(short8*)(wp + 8)  = cv1;
        *(short8*)(wp + 16) = cv2;
        *(short8*)(wp + 24) = cv3;

        const short* vrow = vbuf + qcol*VST;
        #pragma unroll
        for (int cI = 0; cI < 2; ++cI) {
            short8 kf = {0,0,0,0,0,0,0,0};
            if (h == 0) {
                short4 kk = cI ? ck1 : ck0;
                kf[0]=kk.x; kf[1]=kk.y; kf[2]=kk.z; kf[3]=kk.w;
            }
            f32x16 s = __builtin_amdgcn_mfma_f32_32x32x16_bf16(kf, qf, zz, 0, 0, 0);
            unsigned int u[8];
            #pragma unroll
            for (int g4 = 0; g4 < 4; ++g4) {
                float p0 = exp2f(s[4*g4]),   p1 = exp2f(s[4*g4+1]);
                float p2 = exp2f(s[4*g4+2]), p3 = exp2f(s[4*g4+3]);
                se += (p0+p1)+(p2+p3);
                u[2*g4]   = pkbf(p0,p1);
                u[2*g4+1] = pkbf(p2,p3);
            }
            int vo = cI*32 + 4*h;
            short4 a0 = *(const short4*)(vrow + vo);
            short4 a1 = *(const short4*)(vrow + vo + 8);
            short4 a2 = *(const short4*)(vrow + vo + 16);
            short4 a3 = *(const short4*)(vrow + vo + 24);
            short8 vf1 = {a0.x,a0.y,a0.z,a0.w, a1.x,a1.y,a1.z,a1.w};
            short8 pf1 = {(short)u[0],(short)(u[0]>>16),(short)u[1],(short)(u[1]>>16),
                          (short)u[2],(short)(u[2]>>16),(short)u[3],(short)(u[3]>>16)};
            acc = __builtin_amdgcn_mfma_f32_32x32x16_bf16(vf1, pf1, acc, 0, 0, 0);
            short8 vf2 = {a2.x,a2.y,a2.z,a2.w, a3.x,a3.y,a3.z,a3.w};
            short8 pf2 = {(short)u[4],(short)(u[4]>>16),(short)u[5],(short)(u[5]>>16),
                          (short)u[6],(short)(u[6]>>16),(short)u[7],(short)(u[7]>>16)};
            acc = __builtin_amdgcn_mfma_f32_32x32x16_bf16(vf2, pf2, acc, 0, 0, 0);
        }
        cv0 = nv0; cv1 = nv1; cv2 = nv2; cv3 = nv3;
        ck0 = nk0; ck1 = nk1;
    }

    se += __shfl_xor(se, 32, 64);   // combine the two key-halves per q

    // ================= lean tail: deposit -> combine -> wave-0 MFMA projection =====
    __syncthreads();                 // all waves done with V buffers
    float* pamw = (float*)smem;      // [16][32][36] XOR-swizzled (73728 B)
    float* pamn = pamw + 16*32*36;   // [32][36] raw channel sums per query
    float* seL  = pamn + 32*36;      // [16][32]
    float* sinv = seL + 512;         // [32]
    float* sbo  = sinv + 32;         // [32]

    {   // deposit: 4 x b128 per thread; channels 4h+8k..+3 are consecutive in acc
        int xq = (qcol & 7) << 2;
        float* pw = pamw + w*1152 + qcol*36;
        f32x4 d0 = {acc[0],acc[1],acc[2],acc[3]};
        f32x4 d1 = {acc[4],acc[5],acc[6],acc[7]};
        f32x4 d2 = {acc[8],acc[9],acc[10],acc[11]};
        f32x4 d3 = {acc[12],acc[13],acc[14],acc[15]};
        *(f32x4*)(pw + ((     4*h) ^ xq)) = d0;
        *(f32x4*)(pw + (( 8 + 4*h) ^ xq)) = d1;
        *(f32x4*)(pw + ((16 + 4*h) ^ xq)) = d2;
        *(f32x4*)(pw + ((24 + 4*h) ^ xq)) = d3;
        if (h == 0) seL[w*32 + qcol] = se;
        if (tid < CC) sbo[tid] = bo[tid];
    }
    __syncthreads();

    if (tid < CC) {                  // 1/sumexp per query
        float s = 0.f;
        #pragma unroll
        for (int w2 = 0; w2 < 16; ++w2) s += seL[w2*32 + tid];
        sinv[tid] = 1.f / s;
    }
    if (tid < 256) {                 // combine: thread (q, cg) sums 16 waves via b128
        int q = tid & 31, cg = tid >> 5;
        int off = (4*cg) ^ ((q & 7) << 2);
        f32x4 s4 = {0.f,0.f,0.f,0.f};
        #pragma unroll
        for (int w2 = 0; w2 < 16; ++w2)
            s4 += *(f32x4*)(pamw + w2*1152 + q*36 + off);
        *(f32x4*)(pamn + q*36 + 4*cg) = s4;
    }
    __syncthreads();

    if (tid < 64) {                  // wave 0: project via 4 MFMAs
        float si = sinv[qcol];
        f32x16 dacc = {0,0,0,0,0,0,0,0,0,0,0,0,0,0,0,0};
        const short* wfb = wfrag + (size_t)b*4*64*8;
        #pragma unroll
        for (int t = 0; t < 4; ++t) {
            short8 af = *(const short8*)(wfb + ((size_t)t*64 + lane)*8);
            short8 zf;
            if (t < 2) {             // Z rows 0..31: sinv * pam channel sums
                f32x4 p0 = *(f32x4*)(pamn + qcol*36 + 16*t + 4*h);
                f32x4 p1 = *(f32x4*)(pamn + qcol*36 + 16*t + 8 + 4*h);
                zf[0] = f2bfr(p0[0]*si); zf[1] = f2bfr(p0[1]*si);
                zf[2] = f2bfr(p0[2]*si); zf[3] = f2bfr(p0[3]*si);
                zf[4] = f2bfr(p1[0]*si); zf[5] = f2bfr(p1[1]*si);
                zf[6] = f2bfr(p1[2]*si); zf[7] = f2bfr(p1[3]*si);
            } else {                 // Z rows 32..63: x tile (read global, coalesced)
                const float* xb2 = x + (size_t)b*CC*NN
                                 + (size_t)(16*(t-2))*NN + i0 + qcol;
                zf[0] = f2bfr(xb2[(size_t)(4*h + 0)*NN]);
                zf[1] = f2bfr(xb2[(size_t)(4*h + 1)*NN]);
                zf[2] = f2bfr(xb2[(size_t)(4*h + 2)*NN]);
                zf[3] = f2bfr(xb2[(size_t)(4*h + 3)*NN]);
                zf[4] = f2bfr(xb2[(size_t)(8 + 4*h + 0)*NN]);
                zf[5] = f2bfr(xb2[(size_t)(8 + 4*h + 1)*NN]);
                zf[6] = f2bfr(xb2[(size_t)(8 + 4*h + 2)*NN]);
                zf[7] = f2bfr(xb2[(size_t)(8 + 4*h + 3)*NN]);
            }
            dacc = __builtin_amdgcn_mfma_f32_32x32x16_bf16(af, zf, dacc, 0, 0, 0);
        }
        float* ob = out + (size_t)b*CC*NN + i0 + qcol;
        #pragma unroll
        for (int r = 0; r < 16; ++r) {
            int o = (r & 3) + 8*(r >> 2) + 4*h;
            ob[(size_t)o*NN] = dacc[r] + sbo[o];
        }
    }
}

extern "C" void kernel_launch(void* const* d_in, const int* in_sizes, int n_in,
                              void* d_out, int out_size, void* d_ws, size_t ws_size,
                              hipStream_t stream)
{
    const float* x  = (const float*)d_in[0];
    const float* wq = (const float*)d_in[1];
    const float* bq = (const float*)d_in[2];
    const float* wk = (const float*)d_in[3];
    const float* bk = (const float*)d_in[4];
    const float* wv = (const float*)d_in[5];
    const float* bv = (const float*)d_in[6];
    const float* gp = (const float*)d_in[7];
    const float* gc = (const float*)d_in[8];
    const float* wo = (const float*)d_in[9];
    const float* bo = (const float*)d_in[10];

    char* wsb = (char*)d_ws;
    short* qpk   = (short*)(wsb + 0);          // 65536 B
    short* kpk   = (short*)(wsb + 65536);      // 65536 B
    short* vbf   = (short*)(wsb + 131072);     // 524288 B
    float* eng   = (float*)(wsb + 655360);     // 8192 B
    short* wfrag = (short*)(wsb + 663552);     // 8192 B  bf16 [2][4][64][8]

    k1<<<328, 256, 0, stream>>>(x, wq, bq, wk, bk, wv, bv, qpk, kpk, vbf, eng);
    kwx<<<BB, 256, 0, stream>>>(eng, wo, gp, gc, wfrag);
    k2<<<BB*128, 1024, 0, stream>>>(qpk, kpk, vbf, wfrag, bo, x, (float*)d_out);
}